// Round 1
// baseline (227.996 us; speedup 1.0000x reference)
//
#include <hip/hip_runtime.h>
#include <hip/hip_bf16.h>

typedef __bf16 bf16x8 __attribute__((ext_vector_type(8)));
typedef float f32x4 __attribute__((ext_vector_type(4)));

#define B_SZ   1024
#define IN_SZ  512
#define HID    128
#define OUT_SZ 64
#define KPAD   544      // 513 padded to 17*32
#define BM     64
#define BN     512
#define BK     32
#define NKT    (KPAD/BK)   // 17
#define APAD   40          // LDS row stride (bf16 elems): 80B = 5*16B -> conflict-free-ish

static __device__ __forceinline__ unsigned short f2bf(float f) {
    __hip_bfloat16 h = __float2bfloat16(f);
    return *reinterpret_cast<unsigned short*>(&h);
}

// Build t_hat (bf16, [1024][544]) and x_hatT (f32, [544][1024]).
__global__ __launch_bounds__(256) void prep_kernel(
    const float* __restrict__ img, const float* __restrict__ tab,
    unsigned short* __restrict__ tbt, float* __restrict__ xhT)
{
    const int blk = blockIdx.x;   // 0..1023
    // t_hat row b = blk   (coalesced read + write)
    for (int j = threadIdx.x; j < KPAD; j += 256) {
        float v = (j == 0) ? 1.0f : (j < 513 ? tab[(size_t)blk * IN_SZ + (j - 1)] : 0.0f);
        tbt[(size_t)blk * KPAD + j] = f2bf(v);
    }
    // x_hatT row i = blk  (coalesced write, gathered read)
    if (blk < KPAD) {
        const int i = blk;
        for (int b = threadIdx.x; b < B_SZ; b += 256) {
            float v = (i == 0) ? 1.0f : (i < 513 ? img[(size_t)b * IN_SZ + (i - 1)] : 0.0f);
            xhT[(size_t)i * B_SZ + b] = v;
        }
    }
}

// C[m, n] = sum_j W1r[m, j] * t_hat[n, j], fused with reduction over i (m = h*513+i)
// weighted by x_hat[n, i], atomically accumulated into y1acc[n*128 + h].
__global__ __launch_bounds__(512) void gemm_fused(
    const float* __restrict__ w1, const unsigned short* __restrict__ tbt,
    const float* __restrict__ xhT, float* __restrict__ y1acc)
{
    __shared__ unsigned short Als[BM][APAD];
    __shared__ unsigned short Bls[BN][APAD];

    const int bm = blockIdx.x >> 1;
    const int bn = blockIdx.x & 1;
    const int m0 = bm * BM;
    const int n0 = bn * BN;
    const int tid  = threadIdx.x;
    const int wv   = tid >> 6;
    const int lane = tid & 63;
    const int l15  = lane & 15;
    const int kg   = lane >> 4;

    const f32x4 zero4 = {0.f, 0.f, 0.f, 0.f};
    f32x4 acc[4][4];
    #pragma unroll
    for (int i = 0; i < 4; ++i)
        #pragma unroll
        for (int j = 0; j < 4; ++j) acc[i][j] = zero4;

    const int ar = tid >> 3;         // 0..63  (A row)
    const int ac = (tid & 7) << 2;   // 0..28  (A col group of 4)

    for (int kt = 0; kt < NKT; ++kt) {
        __syncthreads();
        // ---- stage A: 64x32 fp32 from W1, convert to bf16 ----
        {
            const int j0 = kt * BK + ac;
            const size_t gb = (size_t)(m0 + ar) * 513 + j0;
            unsigned short u0, u1, u2, u3;
            if (kt < NKT - 1) {
                u0 = f2bf(w1[gb + 0]); u1 = f2bf(w1[gb + 1]);
                u2 = f2bf(w1[gb + 2]); u3 = f2bf(w1[gb + 3]);
            } else {
                u0 = (j0 + 0 < 513) ? f2bf(w1[gb + 0]) : (unsigned short)0;
                u1 = (j0 + 1 < 513) ? f2bf(w1[gb + 1]) : (unsigned short)0;
                u2 = (j0 + 2 < 513) ? f2bf(w1[gb + 2]) : (unsigned short)0;
                u3 = (j0 + 3 < 513) ? f2bf(w1[gb + 3]) : (unsigned short)0;
            }
            Als[ar][ac + 0] = u0; Als[ar][ac + 1] = u1;
            Als[ar][ac + 2] = u2; Als[ar][ac + 3] = u3;
        }
        // ---- stage B: 512x32 bf16 from prepacked t_hat ----
        {
            const uint4* src = reinterpret_cast<const uint4*>(
                tbt + (size_t)(n0 + tid) * KPAD + kt * BK);
            uint4 v0 = src[0], v1 = src[1], v2 = src[2], v3 = src[3];
            uint4* dst = reinterpret_cast<uint4*>(&Bls[tid][0]);
            dst[0] = v0; dst[1] = v1; dst[2] = v2; dst[3] = v3;
        }
        __syncthreads();
        // ---- fragments + 16 MFMA ----
        bf16x8 af[4], bfr[4];
        #pragma unroll
        for (int ms = 0; ms < 4; ++ms)
            af[ms] = *reinterpret_cast<const bf16x8*>(&Als[ms * 16 + l15][kg * 8]);
        #pragma unroll
        for (int ns = 0; ns < 4; ++ns)
            bfr[ns] = *reinterpret_cast<const bf16x8*>(&Bls[wv * 64 + ns * 16 + l15][kg * 8]);
        #pragma unroll
        for (int ms = 0; ms < 4; ++ms)
            #pragma unroll
            for (int ns = 0; ns < 4; ++ns)
                acc[ms][ns] = __builtin_amdgcn_mfma_f32_16x16x32_bf16(
                    af[ms], bfr[ns], acc[ms][ns], 0, 0, 0);
    }

    // ---- fused epilogue: y1[n, h] += sum_i C[h*513+i, n] * x_hat[n, i] ----
    const int h0 = m0 / 513;            // uniform per block
    const int mb = (h0 + 1) * 513;      // h boundary
    const bool cross = (mb < m0 + BM);
    #pragma unroll
    for (int ns = 0; ns < 4; ++ns) {
        const int ncol = n0 + wv * 64 + ns * 16 + l15;
        float s0 = 0.f, s1 = 0.f;
        #pragma unroll
        for (int ms = 0; ms < 4; ++ms) {
            #pragma unroll
            for (int v = 0; v < 4; ++v) {
                const int m = m0 + ms * 16 + kg * 4 + v;
                const bool lo = (m < mb);
                const int i = lo ? (m - h0 * 513) : (m - mb);
                const float xv = xhT[(size_t)i * B_SZ + ncol];
                const float val = acc[ms][ns][v] * xv;
                if (lo) s0 += val; else s1 += val;
            }
        }
        s0 += __shfl_xor(s0, 16); s0 += __shfl_xor(s0, 32);
        if (lane < 16) atomicAdd(&y1acc[(size_t)ncol * HID + h0], s0);
        if (cross) {
            s1 += __shfl_xor(s1, 16); s1 += __shfl_xor(s1, 32);
            if (lane < 16 && (h0 + 1) < HID)
                atomicAdd(&y1acc[(size_t)ncol * HID + h0 + 1], s1);
        }
    }
}

// Small MLP tail: y2 = tanh((y1+b1) @ W2^T + b2); out = relu(y2 @ W3^T + b3)
__global__ __launch_bounds__(128) void mlp_kernel(
    const float* __restrict__ y1acc, const float* __restrict__ b1,
    const float* __restrict__ W2, const float* __restrict__ b2,
    const float* __restrict__ W3, const float* __restrict__ b3,
    float* __restrict__ out)
{
    __shared__ float y1r[HID];
    __shared__ float y2r[HID];
    const int b = blockIdx.x;
    const int h = threadIdx.x;
    y1r[h] = y1acc[(size_t)b * HID + h] + b1[h];
    __syncthreads();
    float a = b2[h];
    const float* w2r = W2 + (size_t)h * HID;
    #pragma unroll 8
    for (int k = 0; k < HID; ++k) a += w2r[k] * y1r[k];
    y2r[h] = tanhf(a);
    __syncthreads();
    if (h < OUT_SZ) {
        float a3 = b3[h];
        const float* w3r = W3 + (size_t)h * HID;
        #pragma unroll 8
        for (int k = 0; k < HID; ++k) a3 += w3r[k] * y2r[k];
        out[(size_t)b * OUT_SZ + h] = fmaxf(a3, 0.f);
    }
}

extern "C" void kernel_launch(void* const* d_in, const int* in_sizes, int n_in,
                              void* d_out, int out_size, void* d_ws, size_t ws_size,
                              hipStream_t stream) {
    const float* img = (const float*)d_in[0];
    const float* tab = (const float*)d_in[1];
    const float* W1  = (const float*)d_in[2];
    const float* b1  = (const float*)d_in[3];
    const float* W2  = (const float*)d_in[4];
    const float* b2  = (const float*)d_in[5];
    const float* W3  = (const float*)d_in[6];
    const float* b3  = (const float*)d_in[7];
    float* out = (float*)d_out;

    char* ws = (char*)d_ws;
    float*          y1acc = (float*)ws;                          // 1024*128*4 = 524288 B
    unsigned short* tbt   = (unsigned short*)(ws + 524288);      // 1024*544*2 = 1114112 B
    float*          xhT   = (float*)(ws + 524288 + 1114112);     // 544*1024*4 = 2228224 B

    hipMemsetAsync(y1acc, 0, (size_t)B_SZ * HID * sizeof(float), stream);
    prep_kernel<<<dim3(1024), dim3(256), 0, stream>>>(img, tab, tbt, xhT);
    gemm_fused<<<dim3(2052), dim3(512), 0, stream>>>(W1, tbt, xhT, y1acc);
    mlp_kernel<<<dim3(1024), dim3(128), 0, stream>>>(y1acc, b1, W2, b2, W3, b3, out);
}

// Round 2
// 216.072 us; speedup vs baseline: 1.0552x; 1.0552x over previous
//
#include <hip/hip_runtime.h>
#include <hip/hip_bf16.h>

typedef __bf16 bf16x8 __attribute__((ext_vector_type(8)));
typedef float f32x4 __attribute__((ext_vector_type(4)));
typedef unsigned short u16x4 __attribute__((ext_vector_type(4)));

typedef __attribute__((address_space(1))) const unsigned int gu32;
typedef __attribute__((address_space(3))) unsigned int lu32;

#define B_SZ   1024
#define IN_SZ  512
#define HID    128
#define OUT_SZ 64
#define M_TOT  65664     // 128 * 513
#define BM     64
#define BN     512
#define BK     32
#define NKT    16        // K main loop = 512; j=512 handled as rank-1 tail

static __device__ __forceinline__ unsigned short f2bf(float f) {
    __hip_bfloat16 h = __float2bfloat16(f);
    return *reinterpret_cast<unsigned short*>(&h);
}

// Build t_hat cols 0..511 (bf16 [1024][512]), tc[n] = t_hat[n,512],
// and x_hatT (f32 [513][1024]).
__global__ __launch_bounds__(256) void prep_kernel(
    const float* __restrict__ img, const float* __restrict__ tab,
    unsigned short* __restrict__ tbt, float* __restrict__ xhT,
    float* __restrict__ tc)
{
    const int blk = blockIdx.x;   // 0..1023
    for (int j = threadIdx.x; j < 512; j += 256) {
        float v = (j == 0) ? 1.0f : tab[(size_t)blk * IN_SZ + (j - 1)];
        tbt[(size_t)blk * 512 + j] = f2bf(v);
    }
    if (threadIdx.x == 0) tc[blk] = tab[(size_t)blk * IN_SZ + 511];
    if (blk < 513) {
        for (int b = threadIdx.x; b < B_SZ; b += 256)
            xhT[(size_t)blk * B_SZ + b] =
                (blk == 0) ? 1.0f : img[(size_t)b * IN_SZ + (blk - 1)];
    }
}

// C[m,n] = sum_{j<512} W1[m,j]*t_hat[n,j]  (bf16 MFMA), then epilogue adds
// the j=512 rank-1 term in fp32 and reduces over i (m = h*513+i) weighted by
// x_hat[n,i] into y1acc[n*128+h] via atomics.
__global__ __launch_bounds__(512, 4) void gemm_fused(
    const float* __restrict__ w1, const unsigned short* __restrict__ tbt,
    const float* __restrict__ xhT, const float* __restrict__ tc,
    float* __restrict__ y1acc)
{
    // chunk-swizzled LDS: phys16Bchunk = (row<<2) | (c ^ ((row>>1)&3))
    __shared__ unsigned short Als[BM * BK];   // 4 KB bf16
    __shared__ unsigned short Bls[BN * BK];   // 32 KB bf16

    const int bm = blockIdx.x >> 1;
    const int bn = blockIdx.x & 1;
    const int m0 = bm * BM;
    const int n0 = bn * BN;
    const int tid  = threadIdx.x;
    const int wv   = tid >> 6;
    const int lane = tid & 63;
    const int l15  = lane & 15;
    const int kg   = lane >> 4;

    // ---- A staging setup (reg path: 4 x f32 load -> cvt -> ds_write_b64) ----
    const int ar  = tid >> 3;         // row 0..63
    const int ac4 = tid & 7;          // 4-float group
    const int achunk = (ar << 2) | ((ac4 >> 1) ^ ((ar >> 1) & 3));
    unsigned short* adst = &Als[achunk * 8 + (ac4 & 1) * 4];
    const float* asrc = w1 + (size_t)(m0 + ar) * 513 + ac4 * 4;

    // ---- B staging setup (global_load_lds x4, source pre-swizzled) ----
    const unsigned short* bsrc[4];
    unsigned short* bdst[4];
    #pragma unroll
    for (int q = 0; q < 4; ++q) {
        const int p  = q * 512 + tid;      // physical 16B chunk index
        const int r  = p >> 2;
        const int cl = (p & 3) ^ ((r >> 1) & 3);
        bsrc[q] = tbt + (size_t)(n0 + r) * 512 + cl * 8;
        bdst[q] = &Bls[(q * 512 + wv * 64) * 8];   // wave-uniform base
    }

    // ---- fragment read offsets (ushort units) ----
    int aoffs[4], boffs[4];
    #pragma unroll
    for (int ms = 0; ms < 4; ++ms) {
        const int row = ms * 16 + l15;
        aoffs[ms] = ((row << 2) | (kg ^ ((row >> 1) & 3))) * 8;
    }
    #pragma unroll
    for (int ns = 0; ns < 4; ++ns) {
        const int row = wv * 64 + ns * 16 + l15;
        boffs[ns] = ((row << 2) | (kg ^ ((row >> 1) & 3))) * 8;
    }

    f32x4 acc[4][4] = {};

    for (int kt = 0; kt < NKT; ++kt) {
        const int k32 = kt * BK;
        __syncthreads();
        #pragma unroll
        for (int q = 0; q < 4; ++q)
            __builtin_amdgcn_global_load_lds(
                (gu32*)(const void*)(bsrc[q] + k32),
                (lu32*)(void*)bdst[q], 16, 0, 0);
        {
            const float f0 = asrc[k32 + 0], f1 = asrc[k32 + 1];
            const float f2 = asrc[k32 + 2], f3 = asrc[k32 + 3];
            u16x4 uv;
            uv[0] = f2bf(f0); uv[1] = f2bf(f1);
            uv[2] = f2bf(f2); uv[3] = f2bf(f3);
            *reinterpret_cast<u16x4*>(adst) = uv;
        }
        __syncthreads();

        bf16x8 af[4], bfr[4];
        #pragma unroll
        for (int ms = 0; ms < 4; ++ms)
            af[ms] = *reinterpret_cast<const bf16x8*>(&Als[aoffs[ms]]);
        #pragma unroll
        for (int ns = 0; ns < 4; ++ns)
            bfr[ns] = *reinterpret_cast<const bf16x8*>(&Bls[boffs[ns]]);
        #pragma unroll
        for (int ms = 0; ms < 4; ++ms)
            #pragma unroll
            for (int ns = 0; ns < 4; ++ns)
                acc[ms][ns] = __builtin_amdgcn_mfma_f32_16x16x32_bf16(
                    af[ms], bfr[ns], acc[ms][ns], 0, 0, 0);
    }

    // ---- epilogue: add j=512 rank-1 term, reduce over i, atomics ----
    const int h0 = m0 / 513;
    const int mb = (h0 + 1) * 513;
    const bool cross = (mb < m0 + BM);

    float wc[4][4];
    #pragma unroll
    for (int ms = 0; ms < 4; ++ms)
        #pragma unroll
        for (int v = 0; v < 4; ++v)
            wc[ms][v] = w1[(size_t)(m0 + ms * 16 + kg * 4 + v) * 513 + 512];

    #pragma unroll
    for (int ns = 0; ns < 4; ++ns) {
        const int ncol = n0 + wv * 64 + ns * 16 + l15;
        const float tv = tc[ncol];
        float s0 = 0.f, s1 = 0.f;
        #pragma unroll
        for (int ms = 0; ms < 4; ++ms) {
            #pragma unroll
            for (int v = 0; v < 4; ++v) {
                const int m = m0 + ms * 16 + kg * 4 + v;
                const bool lo = (m < mb);
                const int i = lo ? (m - h0 * 513) : (m - mb);
                const float xv = xhT[(size_t)i * B_SZ + ncol];
                const float val = (acc[ms][ns][v] + wc[ms][v] * tv) * xv;
                if (lo) s0 += val; else s1 += val;
            }
        }
        s0 += __shfl_xor(s0, 16); s0 += __shfl_xor(s0, 32);
        if (lane < 16) atomicAdd(&y1acc[(size_t)ncol * HID + h0], s0);
        if (cross) {
            s1 += __shfl_xor(s1, 16); s1 += __shfl_xor(s1, 32);
            if (lane < 16 && (h0 + 1) < HID)
                atomicAdd(&y1acc[(size_t)ncol * HID + h0 + 1], s1);
        }
    }
}

// y2 = tanh((y1+b1) @ W2^T + b2); out = relu(y2 @ W3^T + b3)
__global__ __launch_bounds__(128) void mlp_kernel(
    const float* __restrict__ y1acc, const float* __restrict__ b1,
    const float* __restrict__ W2, const float* __restrict__ b2,
    const float* __restrict__ W3, const float* __restrict__ b3,
    float* __restrict__ out)
{
    __shared__ float y1r[HID];
    __shared__ float y2r[HID];
    const int b = blockIdx.x;
    const int h = threadIdx.x;
    y1r[h] = y1acc[(size_t)b * HID + h] + b1[h];
    __syncthreads();
    float a = b2[h];
    const float* w2r = W2 + (size_t)h * HID;
    #pragma unroll 8
    for (int k = 0; k < HID; ++k) a += w2r[k] * y1r[k];
    y2r[h] = tanhf(a);
    __syncthreads();
    if (h < OUT_SZ) {
        float a3 = b3[h];
        const float* w3r = W3 + (size_t)h * HID;
        #pragma unroll 8
        for (int k = 0; k < HID; ++k) a3 += w3r[k] * y2r[k];
        out[(size_t)b * OUT_SZ + h] = fmaxf(a3, 0.f);
    }
}

extern "C" void kernel_launch(void* const* d_in, const int* in_sizes, int n_in,
                              void* d_out, int out_size, void* d_ws, size_t ws_size,
                              hipStream_t stream) {
    const float* img = (const float*)d_in[0];
    const float* tab = (const float*)d_in[1];
    const float* W1  = (const float*)d_in[2];
    const float* b1  = (const float*)d_in[3];
    const float* W2  = (const float*)d_in[4];
    const float* b2  = (const float*)d_in[5];
    const float* W3  = (const float*)d_in[6];
    const float* b3  = (const float*)d_in[7];
    float* out = (float*)d_out;

    char* ws = (char*)d_ws;
    float*          y1acc = (float*)ws;                        // 524288 B
    unsigned short* tbt   = (unsigned short*)(ws + 524288);    // 1048576 B
    float*          xhT   = (float*)(ws + 1572864);            // 2101248 B
    float*          tc    = (float*)(ws + 3674112);            // 4096 B

    hipMemsetAsync(y1acc, 0, (size_t)B_SZ * HID * sizeof(float), stream);
    prep_kernel<<<dim3(1024), dim3(256), 0, stream>>>(img, tab, tbt, xhT, tc);
    gemm_fused<<<dim3(2052), dim3(512), 0, stream>>>(W1, tbt, xhT, tc, y1acc);
    mlp_kernel<<<dim3(1024), dim3(128), 0, stream>>>(y1acc, b1, W2, b2, W3, b3, out);
}

// Round 3
// 201.386 us; speedup vs baseline: 1.1321x; 1.0729x over previous
//
#include <hip/hip_runtime.h>
#include <hip/hip_bf16.h>

typedef __bf16 bf16x8 __attribute__((ext_vector_type(8)));
typedef float f32x4 __attribute__((ext_vector_type(4)));
typedef unsigned short u16x8 __attribute__((ext_vector_type(8)));

typedef __attribute__((address_space(1))) const unsigned int gu32;
typedef __attribute__((address_space(3))) unsigned int lu32;

#define B_SZ   1024
#define IN_SZ  512
#define HID    128
#define OUT_SZ 64
#define BM     64
#define BN     512
#define BK     32
#define NKT    16        // K main loop = 512; j=512 handled as rank-1 tail

static __device__ __forceinline__ unsigned short f2bf(float f) {
    __hip_bfloat16 h = __float2bfloat16(f);
    return *reinterpret_cast<unsigned short*>(&h);
}

// Build t_hat cols 0..511 (bf16 [1024][512]), tc[n] = t_hat[n,512],
// and x_hatT (f32 [513][1024]).
__global__ __launch_bounds__(256) void prep_kernel(
    const float* __restrict__ img, const float* __restrict__ tab,
    unsigned short* __restrict__ tbt, float* __restrict__ xhT,
    float* __restrict__ tc)
{
    const int blk = blockIdx.x;   // 0..1023
    for (int j = threadIdx.x; j < 512; j += 256) {
        float v = (j == 0) ? 1.0f : tab[(size_t)blk * IN_SZ + (j - 1)];
        tbt[(size_t)blk * 512 + j] = f2bf(v);
    }
    if (threadIdx.x == 0) tc[blk] = tab[(size_t)blk * IN_SZ + 511];
    if (blk < 513) {
        for (int b = threadIdx.x; b < B_SZ; b += 256)
            xhT[(size_t)blk * B_SZ + b] =
                (blk == 0) ? 1.0f : img[(size_t)b * IN_SZ + (blk - 1)];
    }
}

// C[m,n] = sum_{j<512} W1[m,j]*t_hat[n,j] (bf16 MFMA, fp32 acc); epilogue
// adds the j=512 rank-1 term in fp32 and reduces over i (m = h*513+i)
// weighted by x_hat[n,i] into y1acc[n*128+h] via atomics.
__global__ __launch_bounds__(512, 4) void gemm_fused(
    const float* __restrict__ w1, const unsigned short* __restrict__ tbt,
    const float* __restrict__ xhT, const float* __restrict__ tc,
    float* __restrict__ y1acc)
{
    // A: fp32, chunk-swizzle phys_c = c ^ (r&7)         (8 chunks/row)
    // B: bf16, chunk-swizzle phys_c = c ^ ((r>>1)&3)    (4 chunks/row)
    __shared__ float          Afs[2][BM * BK];   // 2 x 8 KB
    __shared__ unsigned short Bls[2][BN * BK];   // 2 x 32 KB

    const int bm = blockIdx.x >> 1;
    const int bn = blockIdx.x & 1;
    const int m0 = bm * BM;
    const int n0 = bn * BN;
    const int tid  = threadIdx.x;
    const int wv   = tid >> 6;
    const int lane = tid & 63;
    const int l15  = lane & 15;
    const int kg   = lane >> 4;

    // ---- A staging: thread stages phys chunk p=tid; source pre-swizzled ----
    const int ar  = tid >> 3;                       // row 0..63
    const int acl = (tid & 7) ^ (ar & 7);           // logical chunk
    const float* asrc = w1 + (size_t)(m0 + ar) * 513 + acl * 4;
    const int aBase = (wv * 64) * 4;                // wave-uniform dst (floats)

    // ---- B staging: 4 phys chunks per thread; source pre-swizzled ----
    const unsigned short* bsrc[4];
    int bBase[4];
    #pragma unroll
    for (int q = 0; q < 4; ++q) {
        const int p  = q * 512 + tid;
        const int r  = p >> 2;
        const int cl = (p & 3) ^ ((r >> 1) & 3);
        bsrc[q] = tbt + (size_t)(n0 + r) * 512 + cl * 8;
        bBase[q] = (q * 512 + wv * 64) * 8;         // wave-uniform dst (u16)
    }

    // ---- fragment read offsets ----
    int aoff0[4], aoff1[4], boffs[4];
    #pragma unroll
    for (int ms = 0; ms < 4; ++ms) {
        const int r = ms * 16 + l15;
        aoff0[ms] = r * 32 + (((kg * 2) + 0) ^ (r & 7)) * 4;   // float units
        aoff1[ms] = r * 32 + (((kg * 2) + 1) ^ (r & 7)) * 4;
    }
    #pragma unroll
    for (int ns = 0; ns < 4; ++ns) {
        const int r = wv * 64 + ns * 16 + l15;
        boffs[ns] = ((r << 2) | (kg ^ ((r >> 1) & 3))) * 8;    // u16 units
    }

    f32x4 acc[4][4] = {};

#define STAGE(BUF, KT) do {                                                  \
        const int k32_ = (KT) * BK;                                          \
        _Pragma("unroll")                                                    \
        for (int q_ = 0; q_ < 4; ++q_)                                       \
            __builtin_amdgcn_global_load_lds(                                \
                (gu32*)(const void*)(bsrc[q_] + k32_),                       \
                (lu32*)(void*)&Bls[BUF][bBase[q_]], 16, 0, 0);               \
        __builtin_amdgcn_global_load_lds(                                    \
            (gu32*)(const void*)(asrc + k32_),                               \
            (lu32*)(void*)&Afs[BUF][aBase], 16, 0, 0);                       \
    } while (0)

    STAGE(0, 0);
    __syncthreads();

    for (int kt = 0; kt < NKT; ++kt) {
        const int cur = kt & 1;
        if (kt + 1 < NKT) STAGE(cur ^ 1, kt + 1);

        const float*          ab = &Afs[cur][0];
        const unsigned short* bb = &Bls[cur][0];

        bf16x8 bfr[4];
        #pragma unroll
        for (int ns = 0; ns < 4; ++ns)
            bfr[ns] = *reinterpret_cast<const bf16x8*>(&bb[boffs[ns]]);

        #pragma unroll
        for (int ms = 0; ms < 4; ++ms) {
            const f32x4 lo = *reinterpret_cast<const f32x4*>(&ab[aoff0[ms]]);
            const f32x4 hi = *reinterpret_cast<const f32x4*>(&ab[aoff1[ms]]);
            u16x8 u;
            u[0] = f2bf(lo[0]); u[1] = f2bf(lo[1]);
            u[2] = f2bf(lo[2]); u[3] = f2bf(lo[3]);
            u[4] = f2bf(hi[0]); u[5] = f2bf(hi[1]);
            u[6] = f2bf(hi[2]); u[7] = f2bf(hi[3]);
            const bf16x8 af = __builtin_bit_cast(bf16x8, u);
            #pragma unroll
            for (int ns = 0; ns < 4; ++ns)
                acc[ms][ns] = __builtin_amdgcn_mfma_f32_16x16x32_bf16(
                    af, bfr[ns], acc[ms][ns], 0, 0, 0);
        }
        __syncthreads();
    }
#undef STAGE

    // ---- epilogue: add j=512 rank-1 term, reduce over i, atomics ----
    const int h0 = m0 / 513;
    const int mb = (h0 + 1) * 513;
    const bool cross = (mb < m0 + BM);

    float wc[4][4];
    #pragma unroll
    for (int ms = 0; ms < 4; ++ms)
        #pragma unroll
        for (int v = 0; v < 4; ++v)
            wc[ms][v] = w1[(size_t)(m0 + ms * 16 + kg * 4 + v) * 513 + 512];

    #pragma unroll
    for (int ns = 0; ns < 4; ++ns) {
        const int ncol = n0 + wv * 64 + ns * 16 + l15;
        const float tv = tc[ncol];
        float s0 = 0.f, s1 = 0.f;
        #pragma unroll
        for (int ms = 0; ms < 4; ++ms) {
            #pragma unroll
            for (int v = 0; v < 4; ++v) {
                const int m = m0 + ms * 16 + kg * 4 + v;
                const bool lo = (m < mb);
                const int i = lo ? (m - h0 * 513) : (m - mb);
                const float xv = xhT[(size_t)i * B_SZ + ncol];
                const float val = (acc[ms][ns][v] + wc[ms][v] * tv) * xv;
                if (lo) s0 += val; else s1 += val;
            }
        }
        s0 += __shfl_xor(s0, 16); s0 += __shfl_xor(s0, 32);
        if (lane < 16) atomicAdd(&y1acc[(size_t)ncol * HID + h0], s0);
        if (cross) {
            s1 += __shfl_xor(s1, 16); s1 += __shfl_xor(s1, 32);
            if (lane < 16 && (h0 + 1) < HID)
                atomicAdd(&y1acc[(size_t)ncol * HID + h0 + 1], s1);
        }
    }
}

// y2 = tanh((y1+b1) @ W2^T + b2); out = relu(y2 @ W3^T + b3)
__global__ __launch_bounds__(128) void mlp_kernel(
    const float* __restrict__ y1acc, const float* __restrict__ b1,
    const float* __restrict__ W2, const float* __restrict__ b2,
    const float* __restrict__ W3, const float* __restrict__ b3,
    float* __restrict__ out)
{
    __shared__ float y1r[HID];
    __shared__ float y2r[HID];
    const int b = blockIdx.x;
    const int h = threadIdx.x;
    y1r[h] = y1acc[(size_t)b * HID + h] + b1[h];
    __syncthreads();
    float a = b2[h];
    const float* w2r = W2 + (size_t)h * HID;
    #pragma unroll 8
    for (int k = 0; k < HID; ++k) a += w2r[k] * y1r[k];
    y2r[h] = tanhf(a);
    __syncthreads();
    if (h < OUT_SZ) {
        float a3 = b3[h];
        const float* w3r = W3 + (size_t)h * HID;
        #pragma unroll 8
        for (int k = 0; k < HID; ++k) a3 += w3r[k] * y2r[k];
        out[(size_t)b * OUT_SZ + h] = fmaxf(a3, 0.f);
    }
}

extern "C" void kernel_launch(void* const* d_in, const int* in_sizes, int n_in,
                              void* d_out, int out_size, void* d_ws, size_t ws_size,
                              hipStream_t stream) {
    const float* img = (const float*)d_in[0];
    const float* tab = (const float*)d_in[1];
    const float* W1  = (const float*)d_in[2];
    const float* b1  = (const float*)d_in[3];
    const float* W2  = (const float*)d_in[4];
    const float* b2  = (const float*)d_in[5];
    const float* W3  = (const float*)d_in[6];
    const float* b3  = (const float*)d_in[7];
    float* out = (float*)d_out;

    char* ws = (char*)d_ws;
    float*          y1acc = (float*)ws;                        // 524288 B
    unsigned short* tbt   = (unsigned short*)(ws + 524288);    // 1048576 B
    float*          xhT   = (float*)(ws + 1572864);            // 2101248 B
    float*          tc    = (float*)(ws + 3674112);            // 4096 B

    hipMemsetAsync(y1acc, 0, (size_t)B_SZ * HID * sizeof(float), stream);
    prep_kernel<<<dim3(1024), dim3(256), 0, stream>>>(img, tab, tbt, xhT, tc);
    gemm_fused<<<dim3(2052), dim3(512), 0, stream>>>(W1, tbt, xhT, tc, y1acc);
    mlp_kernel<<<dim3(1024), dim3(128), 0, stream>>>(y1acc, b1, W2, b2, W3, b3, out);
}